// Round 9
// baseline (140.922 us; speedup 1.0000x reference)
//
#include <hip/hip_runtime.h>

#define MDIM 512
#define NDIM 8192
#define KDIM 8192

typedef float v4f __attribute__((ext_vector_type(4)));
typedef int   v4i __attribute__((ext_vector_type(4)));
typedef char  c16 __attribute__((ext_vector_type(16)));

#define GLDS16(g, l)                                                    \
  __builtin_amdgcn_global_load_lds(                                     \
      (const __attribute__((address_space(1))) void*)(g),               \
      (__attribute__((address_space(3))) void*)(l), 16, 0, 0)
#define SB __builtin_amdgcn_sched_barrier(0)

// Swizzled byte offset for int8 tiles with 128B rows (BK=128): 8 slots of
// 16B per row, slot XOR'd with (row&7). Lanes 0..15 of a frag-read hit rows
// 0..15 at one k-slot -> swizzle spreads them over all 32 banks (2-way
// aliasing only = free). Producers write this layout to memory; gemm's
// global_load_lds copies it linearly; ds_read applies the same formula.
__device__ __forceinline__ int swz128(int r, int slot) {
  return r * 128 + (((slot ^ (r & 7)) & 7) << 4);
}

// wq int32 -> int8, tiled w8[nt(128)][kt(64)][64r x 128B], swizzled.
// Pure streaming low-byte extract; source fully coalesced.
__global__ __launch_bounds__(256) void compress_w_kernel(
    const int* __restrict__ wq, char* __restrict__ w8) {
  const int tid = blockIdx.x * 256 + threadIdx.x;
  const int R = tid >> 9;     // weight row 0..8191
  const int k16 = tid & 511;  // 16-int group
  const int* src = wq + ((size_t)R << 13) + k16 * 16;
  v4i a[4];
#pragma unroll
  for (int h = 0; h < 4; ++h) a[h] = *(const v4i*)(src + h * 4);
  c16 q;
#pragma unroll
  for (int h = 0; h < 4; ++h) {
    q[h * 4 + 0] = (char)a[h][0];
    q[h * 4 + 1] = (char)a[h][1];
    q[h * 4 + 2] = (char)a[h][2];
    q[h * 4 + 3] = (char)a[h][3];
  }
  const int nt = R >> 6, r = R & 63;
  const int kt = k16 >> 3, g = k16 & 7;
  *(c16*)(w8 + ((size_t)(nt * 64 + kt) << 13) + swz128(r, g)) = q;
}

// x fp32 -> int8 per-row scale ax[m]; tiled xq[mt(4)][kt(64)][128r x 128B].
__global__ __launch_bounds__(256) void quant_x_kernel(
    const float* __restrict__ x, char* __restrict__ xq, float* __restrict__ ax) {
  const int m = blockIdx.x;
  const int t = threadIdx.x;
  const float* row = x + ((size_t)m << 13);
  v4f v[8];
  float mx = 0.f;
#pragma unroll
  for (int i = 0; i < 8; ++i) {
    v[i] = *(const v4f*)(row + t * 32 + i * 4);
#pragma unroll
    for (int r = 0; r < 4; ++r) mx = fmaxf(mx, fabsf(v[i][r]));
  }
#pragma unroll
  for (int d = 1; d < 64; d <<= 1) mx = fmaxf(mx, __shfl_xor(mx, d));
  __shared__ float smx[4];
  if ((t & 63) == 0) smx[t >> 6] = mx;
  __syncthreads();
  mx = fmaxf(fmaxf(smx[0], smx[1]), fmaxf(smx[2], smx[3]));
  const float inv = (mx > 0.f) ? 127.f / mx : 0.f;
  if (t == 0) ax[m] = mx / 127.f;
  const int mt = m >> 7, r = m & 127;
#pragma unroll
  for (int g2 = 0; g2 < 2; ++g2) {
    c16 q;
#pragma unroll
    for (int e = 0; e < 16; ++e) {
      const int idx = g2 * 4 + (e >> 2);
      float f = fminf(fmaxf(v[idx][e & 3] * inv, -127.f), 127.f);
      q[e] = (char)__float2int_rn(f);
    }
    const int k16 = t * 2 + g2;
    const int kt = k16 >> 3, g = k16 & 7;
    *(c16*)(xq + ((size_t)(mt * 64 + kt) << 14) + swz128(r, g)) = q;
  }
}

template <int KS>
__global__ __launch_bounds__(256) void reduce_kernel(const float* __restrict__ p,
                                                     float* __restrict__ out) {
  const size_t i = ((size_t)blockIdx.x * 256 + threadIdx.x) * 4;
  v4f a = *(const v4f*)(p + i);
#pragma unroll
  for (int s = 1; s < KS; ++s) a += *(const v4f*)(p + (size_t)s * MDIM * NDIM + i);
  *(v4f*)(out + i) = a;
}

// Pure-i8 GEMM, BK=128 fat phases: BM=128, BN=64, 4 waves (64m x 32n each).
// Per phase/wave: 6 glds (A4+B2), 12 ds_read_b128, 16 mfma_i32_16x16x64_i8.
// Counted vmcnt(6) double-buffer; scale block (k128) == one phase -> fold
// facc = fma(sc, acc) per phase; ax at epilogue.
template <int KS>
__global__ __launch_bounds__(256, 3) void gemm_i8_kernel(
    const char* __restrict__ xq, const char* __restrict__ w8,
    const float* __restrict__ wsc, const float* __restrict__ ax,
    float* __restrict__ outp) {
  constexpr int NKT = 64 / KS;  // phases of k128
  __shared__ char lA[2][16384];
  __shared__ char lB[2][8192];

  // XCD swizzle: XCD c owns nt in [c*16, c*16+16) x all mt,kh.
  const int b = blockIdx.x;
  const int c = b & 7;
  const int s = b >> 3;
  const int mt = s & 3;
  const int kh = (KS > 1) ? ((s >> 2) & (KS - 1)) : 0;
  const int nt = c * 16 + (s >> (KS > 1 ? 3 : 2));
  const int m0 = mt * 128, n0 = nt * 64;
  const int kt0 = kh * NKT;

  const int t = threadIdx.x;
  const int w = t >> 6, l = t & 63;
  const int wm = (w >> 1) * 64, wn = (w & 1) * 32;
  const int l15 = l & 15, q = l >> 4;

  const char* asrc = xq + ((size_t)(mt * 64 + kt0) << 14);
  const char* bsrc = w8 + ((size_t)(nt * 64 + kt0) << 13);

  v4i acc[4][2] = {};
  v4f facc[4][2] = {};

  auto issue = [&](int tt) {
    const int buf = tt & 1;
#pragma unroll
    for (int it = 0; it < 4; ++it) {
      const int ub = w * 256 + it * 64;  // wave-uniform 16B-unit base
      GLDS16(asrc + ((size_t)tt << 14) + (size_t)(ub + l) * 16, &lA[buf][ub * 16]);
    }
#pragma unroll
    for (int it = 0; it < 2; ++it) {
      const int ub = w * 128 + it * 64;
      GLDS16(bsrc + ((size_t)tt << 13) + (size_t)(ub + l) * 16, &lB[buf][ub * 16]);
    }
  };

  issue(0);
#pragma unroll 1
  for (int tt = 0; tt < NKT; ++tt) {
    const int cur = tt & 1;
    SB;
    __builtin_amdgcn_s_barrier();  // all waves done reading buf[cur^1]
    SB;
    if (tt + 1 < NKT) issue(tt + 1);  // -> buf[cur^1], stays in flight
    SB;
    if (tt + 1 < NKT)
      asm volatile("s_waitcnt vmcnt(6)" ::: "memory");  // tile tt landed
    else
      asm volatile("s_waitcnt vmcnt(0)" ::: "memory");
    SB;
    __builtin_amdgcn_s_barrier();  // buf[cur] visible to all waves
    SB;

#pragma unroll
    for (int kk = 0; kk < 2; ++kk) {  // per-kk frags: lower live range
      v4i af[4], bq[2];
#pragma unroll
      for (int i = 0; i < 4; ++i)
        af[i] = *(const v4i*)&lA[cur][swz128(wm + i * 16 + l15, kk * 4 + q)];
#pragma unroll
      for (int j = 0; j < 2; ++j)
        bq[j] = *(const v4i*)&lB[cur][swz128(wn + j * 16 + l15, kk * 4 + q)];
#pragma unroll
      for (int i = 0; i < 4; ++i)
#pragma unroll
        for (int j = 0; j < 2; ++j)
          acc[i][j] = __builtin_amdgcn_mfma_i32_16x16x64_i8(
              af[i], bq[j], acc[i][j], 0, 0, 0);
    }

    const float sc = wsc[(nt >> 1) * 64 + kt0 + tt];  // this phase's k128
#pragma unroll
    for (int i = 0; i < 4; ++i)
#pragma unroll
      for (int j = 0; j < 2; ++j) {
#pragma unroll
        for (int r = 0; r < 4; ++r)
          facc[i][j][r] = fmaf(sc, (float)acc[i][j][r], facc[i][j][r]);
        acc[i][j] = v4i{0, 0, 0, 0};
      }
  }

  float* dst = outp + ((KS > 1) ? (size_t)kh * MDIM * NDIM : 0);
#pragma unroll
  for (int i = 0; i < 4; ++i) {
    const int mrow = m0 + wm + i * 16 + (l >> 4) * 4;
#pragma unroll
    for (int j = 0; j < 2; ++j) {
      const int ocol = n0 + wn + j * 16 + l15;
#pragma unroll
      for (int r = 0; r < 4; ++r)
        dst[(size_t)(mrow + r) * NDIM + ocol] = ax[mrow + r] * facc[i][j][r];
    }
  }
}

extern "C" void kernel_launch(void* const* d_in, const int* in_sizes, int n_in,
                              void* d_out, int out_size, void* d_ws,
                              size_t ws_size, hipStream_t stream) {
  const float* x = (const float*)d_in[0];
  const int* wq = (const int*)d_in[1];
  const float* wsc = (const float*)d_in[2];
  float* out = (float*)d_out;

  const size_t W8 = (size_t)NDIM * KDIM;      // 64 MB
  const size_t XQ = (size_t)MDIM * KDIM;      // 4 MB
  const size_t AX = 65536;                    // padded
  const size_t PS = (size_t)MDIM * NDIM * 4;  // 16 MB per partial

  char* w8 = (char*)d_ws;
  char* xq = (char*)d_ws + W8;
  float* ax = (float*)((char*)d_ws + W8 + XQ);
  float* part = (float*)((char*)d_ws + W8 + XQ + AX);

  compress_w_kernel<<<dim3((NDIM * (KDIM / 16)) / 256), dim3(256), 0, stream>>>(wq, w8);
  quant_x_kernel<<<dim3(MDIM), dim3(256), 0, stream>>>(x, xq, ax);

  if (ws_size >= W8 + XQ + AX + 2 * PS) {
    gemm_i8_kernel<2><<<dim3(1024), dim3(256), 0, stream>>>(xq, w8, wsc, ax, part);
    reduce_kernel<2><<<dim3((MDIM * NDIM) / (256 * 4)), dim3(256), 0, stream>>>(part, out);
  } else {
    gemm_i8_kernel<1><<<dim3(512), dim3(256), 0, stream>>>(xq, w8, wsc, ax, out);
  }
}